// Round 1
// baseline (975.356 us; speedup 1.0000x reference)
//
#include <hip/hip_runtime.h>

#define NSEQ 256
#define NRES 1024
#define CM   256
#define CC   32
#define CZ   128
#define EPS  1e-5f
#define SROW (NRES * CM)   // stride between s-rows of x for fixed r

// One block per residue r. 256 threads.
// Phases:
//  P0: stage w_t[m][c] = nw[m]*w_ab[c][m] in LDS; compute K1/K2.
//  P1: G = x_r @ w'^T (8s x 4c per thread) + per-s sum/sumsq in same pass.
//  P2: finalize a[s][c] = rstd*(G - mu*K1) + K2, store to LDS (reuse w_t buf).
//  P3: o[x][y] = mean_s a[s][x]*a[s][y], 2x2 tile per thread.
//  P4: pre[z] = o_flat . w_out[z] + b_out[z].
//  P5: broadcast pre over 1024 output rows (coalesced float4 stores).
__launch_bounds__(256, 4)
__global__ void opm_fused(const float* __restrict__ msa,
                          const float* __restrict__ nw,
                          const float* __restrict__ nb,
                          const float* __restrict__ w_ab,
                          const float* __restrict__ b_ab,
                          const float* __restrict__ w_out,
                          const float* __restrict__ b_out,
                          float* __restrict__ out)
{
    __shared__ float buf[CM * CC];      // 32 KB: w_t[m][c], later a[s][c]
    __shared__ float K1[CC], K2[CC];
    __shared__ float o_lds[CC * CC];    // 4 KB
    __shared__ float pre_part[2 * CZ];
    __shared__ float pre_lds[CZ];

    const int tid = threadIdx.x;
    const int r   = blockIdx.x;

    // ---------------- P0: stage w' transposed ----------------
    {
        const int c  = tid & 31;
        const int m0 = tid >> 5;            // 0..7
        #pragma unroll
        for (int k = 0; k < 32; ++k) {
            const int m = m0 + (k << 3);    // covers 0..255
            buf[m * CC + c] = nw[m] * w_ab[c * CM + m];   // LDS write: consecutive c -> conflict-free
        }
    }
    __syncthreads();
    if (tid < CC) {
        const int c = tid;
        float k1 = 0.f, k2 = 0.f;
        for (int m = 0; m < CM; ++m) {
            k1 += buf[m * CC + c];
            k2 = fmaf(nb[m], w_ab[c * CM + m], k2);
        }
        K1[c] = k1;
        K2[c] = k2 + b_ab[c];
    }
    __syncthreads();

    // ---------------- P1: G-phase ----------------
    const int sc = tid & 7;
    const int sg = tid >> 3;                // 0..31 ; s = sg + 32*j
    const int c0 = sc * 4;
    const float* xr = msa + (size_t)r * CM; // x[s][m] = xr[s*SROW + m]

    float G[8][4];
    float ssum[8], ssq[8];
    #pragma unroll
    for (int j = 0; j < 8; ++j) {
        ssum[j] = 0.f; ssq[j] = 0.f;
        #pragma unroll
        for (int cc = 0; cc < 4; ++cc) G[j][cc] = 0.f;
    }

    const float* xrow[8];
    #pragma unroll
    for (int j = 0; j < 8; ++j)
        xrow[j] = xr + (size_t)(sg + (j << 5)) * SROW;

    for (int mb = 0; mb < CM; mb += 4) {
        const float4 w0 = *(const float4*)&buf[(mb + 0) * CC + c0];
        const float4 w1 = *(const float4*)&buf[(mb + 1) * CC + c0];
        const float4 w2 = *(const float4*)&buf[(mb + 2) * CC + c0];
        const float4 w3 = *(const float4*)&buf[(mb + 3) * CC + c0];
        float4 xv[8];
        #pragma unroll
        for (int j = 0; j < 8; ++j)
            xv[j] = *(const float4*)(xrow[j] + mb);
        #pragma unroll
        for (int j = 0; j < 8; ++j) {
            const float4 x4 = xv[j];
            G[j][0] = fmaf(x4.x, w0.x, fmaf(x4.y, w1.x, fmaf(x4.z, w2.x, fmaf(x4.w, w3.x, G[j][0]))));
            G[j][1] = fmaf(x4.x, w0.y, fmaf(x4.y, w1.y, fmaf(x4.z, w2.y, fmaf(x4.w, w3.y, G[j][1]))));
            G[j][2] = fmaf(x4.x, w0.z, fmaf(x4.y, w1.z, fmaf(x4.z, w2.z, fmaf(x4.w, w3.z, G[j][2]))));
            G[j][3] = fmaf(x4.x, w0.w, fmaf(x4.y, w1.w, fmaf(x4.z, w2.w, fmaf(x4.w, w3.w, G[j][3]))));
            ssum[j] += (x4.x + x4.y) + (x4.z + x4.w);
            ssq[j]  = fmaf(x4.x, x4.x, fmaf(x4.y, x4.y, fmaf(x4.z, x4.z, fmaf(x4.w, x4.w, ssq[j]))));
        }
    }

    // ---------------- P2: finalize a, store to LDS (reuse buf) ----------------
    float a_reg[8][4];
    {
        const float k1a = K1[c0 + 0], k1b = K1[c0 + 1], k1c = K1[c0 + 2], k1d = K1[c0 + 3];
        const float k2a = K2[c0 + 0], k2b = K2[c0 + 1], k2c = K2[c0 + 2], k2d = K2[c0 + 3];
        #pragma unroll
        for (int j = 0; j < 8; ++j) {
            const float mu   = ssum[j] * (1.f / CM);
            const float var  = ssq[j] * (1.f / CM) - mu * mu;
            const float rstd = 1.f / sqrtf(var + EPS);
            a_reg[j][0] = fmaf(rstd, G[j][0] - mu * k1a, k2a);
            a_reg[j][1] = fmaf(rstd, G[j][1] - mu * k1b, k2b);
            a_reg[j][2] = fmaf(rstd, G[j][2] - mu * k1c, k2c);
            a_reg[j][3] = fmaf(rstd, G[j][3] - mu * k1d, k2d);
        }
    }
    __syncthreads();   // all w_t reads done before overwrite
    #pragma unroll
    for (int j = 0; j < 8; ++j) {
        const int s = sg + (j << 5);
        *(float4*)&buf[s * CC + c0] =
            make_float4(a_reg[j][0], a_reg[j][1], a_reg[j][2], a_reg[j][3]);
    }
    __syncthreads();

    // ---------------- P3: o = A^T A / NSEQ, 2x2 tile per thread ----------------
    const int xi = (tid >> 4) << 1;   // 0,2,..,30
    const int yi = (tid & 15) << 1;   // 0,2,..,30
    float o00 = 0.f, o01 = 0.f, o10 = 0.f, o11 = 0.f;
    #pragma unroll 4
    for (int s = 0; s < NSEQ; ++s) {
        const float2 ax = *(const float2*)&buf[s * CC + xi];
        const float2 ay = *(const float2*)&buf[s * CC + yi];
        o00 = fmaf(ax.x, ay.x, o00);
        o01 = fmaf(ax.x, ay.y, o01);
        o10 = fmaf(ax.y, ay.x, o10);
        o11 = fmaf(ax.y, ay.y, o11);
    }
    {
        const float inv_s = 1.f / NSEQ;
        *(float2*)&o_lds[xi * CC + yi]       = make_float2(o00 * inv_s, o01 * inv_s);
        *(float2*)&o_lds[(xi + 1) * CC + yi] = make_float2(o10 * inv_s, o11 * inv_s);
    }
    __syncthreads();

    // ---------------- P4: pre[z] = o . w_out[z] + b_out[z] ----------------
    {
        const int z    = tid & 127;
        const int half = tid >> 7;
        const float* wrow = w_out + (size_t)z * (CC * CC) + half * 512;
        const float* op   = o_lds + half * 512;
        float po = 0.f;
        for (int k = 0; k < 512; k += 4) {
            const float4 o4 = *(const float4*)&op[k];
            const float4 w4 = *(const float4*)&wrow[k];
            po = fmaf(o4.x, w4.x, fmaf(o4.y, w4.y, fmaf(o4.z, w4.z, fmaf(o4.w, w4.w, po))));
        }
        pre_part[half * CZ + z] = po;
    }
    __syncthreads();
    if (tid < CZ) pre_lds[tid] = pre_part[tid] + pre_part[CZ + tid] + b_out[tid];
    __syncthreads();

    // ---------------- P5: broadcast write ----------------
    {
        const int z4 = tid & 31;        // which float4 of the 128-float row
        const int jo = tid >> 5;        // 0..7
        const float4 pv = *(const float4*)&pre_lds[z4 * 4];
        float4* outp = (float4*)out + (size_t)r * NRES * (CZ / 4);
        for (int j0 = 0; j0 < NRES; j0 += 8) {
            outp[(size_t)(j0 + jo) * (CZ / 4) + z4] = pv;
        }
    }
}

extern "C" void kernel_launch(void* const* d_in, const int* in_sizes, int n_in,
                              void* d_out, int out_size, void* d_ws, size_t ws_size,
                              hipStream_t stream) {
    const float* msa   = (const float*)d_in[0];
    const float* nw    = (const float*)d_in[1];
    const float* nb    = (const float*)d_in[2];
    const float* w_ab  = (const float*)d_in[3];
    const float* b_ab  = (const float*)d_in[4];
    const float* w_out = (const float*)d_in[5];
    const float* b_out = (const float*)d_in[6];
    float* out = (float*)d_out;

    opm_fused<<<NRES, 256, 0, stream>>>(msa, nw, nb, w_ab, b_ab, w_out, b_out, out);
}

// Round 3
// 840.266 us; speedup vs baseline: 1.1608x; 1.1608x over previous
//
#include <hip/hip_runtime.h>

#define NSEQ 256
#define NRES 1024
#define CM   256
#define CC   32
#define CZ   128
#define EPS  1e-5f
#define SROW (NRES * CM)   // stride between s-rows of x for fixed r
#define MCH  32            // m-chunk size (floats)
#define XPAD 36            // padded row stride for x chunk (floats): +4 spreads banks

typedef float f4v __attribute__((ext_vector_type(4)));  // native vec for nontemporal builtin

// One block per residue r. 256 threads, 2 blocks/CU (LDS-limited).
// Phases:
//  P0: stage w_t[m][c] = nw[m]*w_ab[c][m] in LDS; parallel K1/K2.
//  P1: G-phase, m-chunked: stage x[0..255][mb..mb+32) in LDS via coalesced
//      128B-per-row loads (full line use), register-double-buffered; compute
//      8s x 4c per thread from LDS + per-s sum/sumsq.
//  P2: finalize a[s][c], store into x-chunk LDS region (stride 32).
//  P3: o = A^T A / NSEQ, 2x2 tile per thread.
//  P4: pre[z] = o . w_out[z] + b_out[z].
//  P5: broadcast pre over 1024 rows, nontemporal float4 stores.
__launch_bounds__(256, 2)
__global__ void opm_fused(const float* __restrict__ msa,
                          const float* __restrict__ nw,
                          const float* __restrict__ nb,
                          const float* __restrict__ w_ab,
                          const float* __restrict__ b_ab,
                          const float* __restrict__ w_out,
                          const float* __restrict__ b_out,
                          float* __restrict__ out)
{
    __shared__ float wt[CM * CC];        // 32 KB  [m][c]
    __shared__ float xt[NSEQ * XPAD];    // 36 KB  x chunk [s][m'] (pad 4); later a[s][c] stride 32
    __shared__ float o_lds[CC * CC];     // 4 KB
    __shared__ float K1p[8 * CC], K2p[8 * CC];
    __shared__ float K1[CC], K2[CC];
    __shared__ float pre_part[2 * CZ];
    __shared__ float pre_lds[CZ];

    const int tid = threadIdx.x;
    const int r   = blockIdx.x;

    // ---------------- P0: stage w' transposed ----------------
    {
        const int c  = tid & 31;
        const int m0 = tid >> 5;            // 0..7
        #pragma unroll
        for (int k = 0; k < 32; ++k) {
            const int m = m0 + (k << 3);    // covers 0..255
            wt[m * CC + c] = nw[m] * w_ab[c * CM + m];
        }
    }
    __syncthreads();
    // parallel K1/K2: thread -> (c, m-part of 32)
    {
        const int c    = tid & 31;
        const int part = tid >> 5;          // 0..7
        float k1 = 0.f, k2 = 0.f;
        #pragma unroll 8
        for (int i = 0; i < 32; ++i) {
            const int m = part * 32 + i;
            k1 += wt[m * CC + c];
            k2 = fmaf(nb[m], w_ab[c * CM + m], k2);
        }
        K1p[part * CC + c] = k1;
        K2p[part * CC + c] = k2;
    }
    __syncthreads();
    if (tid < CC) {
        float k1 = 0.f, k2 = 0.f;
        #pragma unroll
        for (int p = 0; p < 8; ++p) { k1 += K1p[p * CC + tid]; k2 += K2p[p * CC + tid]; }
        K1[tid] = k1;
        K2[tid] = k2 + b_ab[tid];
    }

    // ---------------- P1: G-phase, m-chunked with register prefetch ----------------
    const int sc = tid & 7;                 // c-group AND staging float4 index
    const int sg = tid >> 3;                // 0..31: row-group AND staging row
    const int c0 = sc * 4;
    const float* xr = msa + (size_t)r * CM; // x[s][m] = xr[s*SROW + m]

    float G[8][4];
    float ssum[8], ssq[8];
    #pragma unroll
    for (int j = 0; j < 8; ++j) {
        ssum[j] = 0.f; ssq[j] = 0.f;
        #pragma unroll
        for (int cc = 0; cc < 4; ++cc) G[j][cc] = 0.f;
    }

    // prologue: prefetch chunk 0 (8 consecutive lanes cover 128B contiguous per row)
    float4 pf[8];
    #pragma unroll
    for (int k = 0; k < 8; ++k)
        pf[k] = *(const float4*)(xr + (size_t)(sg + (k << 5)) * SROW + (sc << 2));

    for (int mb = 0; mb < CM; mb += MCH) {
        __syncthreads();   // previous chunk's readers done
        #pragma unroll
        for (int k = 0; k < 8; ++k)
            *(float4*)&xt[(sg + (k << 5)) * XPAD + (sc << 2)] = pf[k];
        __syncthreads();
        if (mb + MCH < CM) {
            #pragma unroll
            for (int k = 0; k < 8; ++k)
                pf[k] = *(const float4*)(xr + (size_t)(sg + (k << 5)) * SROW + (mb + MCH) + (sc << 2));
        }
        #pragma unroll
        for (int mm = 0; mm < MCH; mm += 4) {
            const float4 w0 = *(const float4*)&wt[(mb + mm + 0) * CC + c0];
            const float4 w1 = *(const float4*)&wt[(mb + mm + 1) * CC + c0];
            const float4 w2 = *(const float4*)&wt[(mb + mm + 2) * CC + c0];
            const float4 w3 = *(const float4*)&wt[(mb + mm + 3) * CC + c0];
            #pragma unroll
            for (int j = 0; j < 8; ++j) {
                const float4 x4 = *(const float4*)&xt[(sg + (j << 5)) * XPAD + mm];
                G[j][0] = fmaf(x4.x, w0.x, fmaf(x4.y, w1.x, fmaf(x4.z, w2.x, fmaf(x4.w, w3.x, G[j][0]))));
                G[j][1] = fmaf(x4.x, w0.y, fmaf(x4.y, w1.y, fmaf(x4.z, w2.y, fmaf(x4.w, w3.y, G[j][1]))));
                G[j][2] = fmaf(x4.x, w0.z, fmaf(x4.y, w1.z, fmaf(x4.z, w2.z, fmaf(x4.w, w3.z, G[j][2]))));
                G[j][3] = fmaf(x4.x, w0.w, fmaf(x4.y, w1.w, fmaf(x4.z, w2.w, fmaf(x4.w, w3.w, G[j][3]))));
                ssum[j] += (x4.x + x4.y) + (x4.z + x4.w);
                ssq[j]  = fmaf(x4.x, x4.x, fmaf(x4.y, x4.y, fmaf(x4.z, x4.z, fmaf(x4.w, x4.w, ssq[j]))));
            }
        }
    }

    // ---------------- P2: finalize a, store into xt (stride 32) ----------------
    float a_reg[8][4];
    {
        const float k1a = K1[c0 + 0], k1b = K1[c0 + 1], k1c = K1[c0 + 2], k1d = K1[c0 + 3];
        const float k2a = K2[c0 + 0], k2b = K2[c0 + 1], k2c = K2[c0 + 2], k2d = K2[c0 + 3];
        #pragma unroll
        for (int j = 0; j < 8; ++j) {
            const float mu   = ssum[j] * (1.f / CM);
            const float var  = ssq[j] * (1.f / CM) - mu * mu;
            const float rstd = 1.f / sqrtf(var + EPS);
            a_reg[j][0] = fmaf(rstd, G[j][0] - mu * k1a, k2a);
            a_reg[j][1] = fmaf(rstd, G[j][1] - mu * k1b, k2b);
            a_reg[j][2] = fmaf(rstd, G[j][2] - mu * k1c, k2c);
            a_reg[j][3] = fmaf(rstd, G[j][3] - mu * k1d, k2d);
        }
    }
    __syncthreads();   // all chunk reads done before overwrite
    #pragma unroll
    for (int j = 0; j < 8; ++j) {
        const int s = sg + (j << 5);
        *(float4*)&xt[s * CC + c0] =
            make_float4(a_reg[j][0], a_reg[j][1], a_reg[j][2], a_reg[j][3]);
    }
    __syncthreads();

    // ---------------- P3: o = A^T A / NSEQ, 2x2 tile per thread ----------------
    const int xi = (tid >> 4) << 1;   // 0,2,..,30
    const int yi = (tid & 15) << 1;   // 0,2,..,30
    float o00 = 0.f, o01 = 0.f, o10 = 0.f, o11 = 0.f;
    #pragma unroll 4
    for (int s = 0; s < NSEQ; ++s) {
        const float2 ax = *(const float2*)&xt[s * CC + xi];
        const float2 ay = *(const float2*)&xt[s * CC + yi];
        o00 = fmaf(ax.x, ay.x, o00);
        o01 = fmaf(ax.x, ay.y, o01);
        o10 = fmaf(ax.y, ay.x, o10);
        o11 = fmaf(ax.y, ay.y, o11);
    }
    {
        const float inv_s = 1.f / NSEQ;
        *(float2*)&o_lds[xi * CC + yi]       = make_float2(o00 * inv_s, o01 * inv_s);
        *(float2*)&o_lds[(xi + 1) * CC + yi] = make_float2(o10 * inv_s, o11 * inv_s);
    }
    __syncthreads();

    // ---------------- P4: pre[z] = o . w_out[z] + b_out[z] ----------------
    {
        const int z    = tid & 127;
        const int half = tid >> 7;
        const float* wrow = w_out + (size_t)z * (CC * CC) + half * 512;
        const float* op   = o_lds + half * 512;
        float po = 0.f;
        #pragma unroll 8
        for (int k = 0; k < 512; k += 4) {
            const float4 o4 = *(const float4*)&op[k];
            const float4 w4 = *(const float4*)&wrow[k];
            po = fmaf(o4.x, w4.x, fmaf(o4.y, w4.y, fmaf(o4.z, w4.z, fmaf(o4.w, w4.w, po))));
        }
        pre_part[half * CZ + z] = po;
    }
    __syncthreads();
    if (tid < CZ) pre_lds[tid] = pre_part[tid] + pre_part[CZ + tid] + b_out[tid];
    __syncthreads();

    // ---------------- P5: broadcast write (nontemporal, native vec type) ----------------
    {
        const int z4 = tid & 31;        // which float4 of the 128-float row
        const int jo = tid >> 5;        // 0..7
        f4v pv;
        pv.x = pre_lds[z4 * 4 + 0];
        pv.y = pre_lds[z4 * 4 + 1];
        pv.z = pre_lds[z4 * 4 + 2];
        pv.w = pre_lds[z4 * 4 + 3];
        f4v* outp = (f4v*)out + (size_t)r * NRES * (CZ / 4);
        for (int j0 = 0; j0 < NRES; j0 += 8) {
            __builtin_nontemporal_store(pv, &outp[(size_t)(j0 + jo) * (CZ / 4) + z4]);
        }
    }
}

extern "C" void kernel_launch(void* const* d_in, const int* in_sizes, int n_in,
                              void* d_out, int out_size, void* d_ws, size_t ws_size,
                              hipStream_t stream) {
    const float* msa   = (const float*)d_in[0];
    const float* nw    = (const float*)d_in[1];
    const float* nb    = (const float*)d_in[2];
    const float* w_ab  = (const float*)d_in[3];
    const float* b_ab  = (const float*)d_in[4];
    const float* w_out = (const float*)d_in[5];
    const float* b_out = (const float*)d_in[6];
    float* out = (float*)d_out;

    opm_fused<<<NRES, 256, 0, stream>>>(msa, nw, nb, w_ab, b_ab, w_out, b_out, out);
}